// Round 4
// baseline (4820.237 us; speedup 1.0000x reference)
//
#include <hip/hip_runtime.h>
#include <math.h>

typedef __attribute__((ext_vector_type(4))) float f32x4;
typedef __attribute__((ext_vector_type(8))) short bf16x8;

__device__ inline short f2bf(float f) {
    union { float f; unsigned u; } v; v.f = f;
    unsigned u = v.u;
    u += 0x7fffu + ((u >> 16) & 1u);   // RNE
    return (short)(u >> 16);
}

struct Params {
    const float *x, *weight, *Wqkv, *Wo, *ln1_g, *ln1_b, *ln2_g, *ln2_b,
                *fc1_w, *fc1_b, *fc2_w, *fc2_b;
    float *ws, *out;
    unsigned *bar;
};

#define NBLK 1024u

// ---- grid barrier: monotonic counter, explicit fences, backoff polling ----
__device__ inline void gsync(unsigned* bar, unsigned target) {
    __syncthreads();
    if (threadIdx.x == 0) {
        __threadfence();   // release: publish this block's writes device-wide
        __hip_atomic_fetch_add(bar, 1u, __ATOMIC_RELAXED, __HIP_MEMORY_SCOPE_AGENT);
        int n = 0;
        while (__hip_atomic_load(bar, __ATOMIC_RELAXED, __HIP_MEMORY_SCOPE_AGENT) < target) {
            if (++n < 8) __builtin_amdgcn_s_sleep(8);
            else         __builtin_amdgcn_s_sleep(64);
        }
        __threadfence();   // acquire
    }
    __syncthreads();
}

// ---- split-K GEMM, KC=256, plain-store partials: pool[by][32][N] = act[32][kc]@W^T ----
__device__ inline void gemm256(const float* __restrict__ W, const float* __restrict__ act,
                               float* __restrict__ pool, int N, int K,
                               short (*lAs)[264], int bid, int t) {
    int nbx = N >> 6;
    int ntask = nbx * (K >> 8);
    int lane = t & 63, wv = t >> 6, m = lane & 15, q = lane >> 4;
    int arow = t >> 3, acol = (t & 7) * 32;
    for (int task = bid; task < (int)ntask; task += NBLK) {
        int bx = task % nbx, by = task / nbx;
        size_t kbeg = (size_t)by << 8;
        int nb = bx * 64 + wv * 16;
        // burst 1: B first half (kc 0..3)
        const float* B = W + (size_t)(nb + m) * K + kbeg + q * 8;
        float4 Bb[16];
        #pragma unroll
        for (int s = 0; s < 4; ++s) {
            Bb[2 * s]     = *(const float4*)(B + s * 32);
            Bb[2 * s + 1] = *(const float4*)(B + s * 32 + 4);
        }
        // burst 2: A (32 floats/thread)
        const float* ap = act + (size_t)arow * K + kbeg + acol;
        float4 ar[8];
        #pragma unroll
        for (int j = 0; j < 8; ++j) ar[j] = *(const float4*)(ap + j * 4);
        // burst 3: B second half (kc 4..7)
        #pragma unroll
        for (int s = 4; s < 8; ++s) {
            Bb[2 * s]     = *(const float4*)(B + s * 32);
            Bb[2 * s + 1] = *(const float4*)(B + s * 32 + 4);
        }
        __syncthreads();   // previous task's lAs readers done
        #pragma unroll
        for (int j = 0; j < 8; ++j) {
            short4 c = { f2bf(ar[j].x), f2bf(ar[j].y), f2bf(ar[j].z), f2bf(ar[j].w) };
            *(short4*)&lAs[arow][acol + j * 4] = c;
        }
        __syncthreads();
        f32x4 acc0 = {0.f, 0.f, 0.f, 0.f};
        f32x4 acc1 = {0.f, 0.f, 0.f, 0.f};
        #pragma unroll
        for (int s = 0; s < 8; ++s) {
            bf16x8 fa0 = *(const bf16x8*)&lAs[m][s * 32 + q * 8];
            bf16x8 fa1 = *(const bf16x8*)&lAs[m + 16][s * 32 + q * 8];
            float4 bl = Bb[2 * s], bh = Bb[2 * s + 1];
            bf16x8 fb = { f2bf(bl.x), f2bf(bl.y), f2bf(bl.z), f2bf(bl.w),
                          f2bf(bh.x), f2bf(bh.y), f2bf(bh.z), f2bf(bh.w) };
            acc0 = __builtin_amdgcn_mfma_f32_16x16x32_bf16(fa0, fb, acc0, 0, 0, 0);
            acc1 = __builtin_amdgcn_mfma_f32_16x16x32_bf16(fa1, fb, acc1, 0, 0, 0);
        }
        // C/D: col = lane&15 (feature nb+m), row = q*4+reg (token).  Plain stores.
        float* op = pool + (size_t)by * 32 * N + (size_t)(q * 4) * N + nb + m;
        #pragma unroll
        for (int r = 0; r < 4; ++r) {
            op[(size_t)r * N] = acc0[r];
            op[(size_t)(r + 16) * N] = acc1[r];
        }
    }
}

// ---- row LayerNorm.  mode 0: out = LN(v).  mode 1: out = LN(v)+v ----
__device__ inline void ln_task(const float* __restrict__ row,
                               const float* __restrict__ g, const float* __restrict__ b,
                               float* __restrict__ outA, int mode, float* red, int t) {
    float v[8];
    #pragma unroll
    for (int j = 0; j < 8; ++j) v[j] = row[j * 256 + t];
    float sm = 0.f, ss = 0.f;
    #pragma unroll
    for (int j = 0; j < 8; ++j) { sm += v[j]; ss += v[j] * v[j]; }
    for (int off = 32; off; off >>= 1) { sm += __shfl_xor(sm, off, 64); ss += __shfl_xor(ss, off, 64); }
    int wv = t >> 6, lane = t & 63;
    if (lane == 0) { red[wv] = sm; red[4 + wv] = ss; }
    __syncthreads();
    sm = red[0] + red[1] + red[2] + red[3];
    ss = red[4] + red[5] + red[6] + red[7];
    float mu = sm * (1.0f / 2048.0f);
    float rstd = rsqrtf(ss * (1.0f / 2048.0f) - mu * mu + 1e-5f);
    #pragma unroll
    for (int j = 0; j < 8; ++j) {
        int col = j * 256 + t;
        float lnv = (v[j] - mu) * rstd * g[col] + b[col];
        outA[col] = mode ? (lnv + v[j]) : lnv;
    }
}

__global__ __launch_bounds__(256, 4) void k_mega(Params P) {
    __shared__ short lAs[32][264];
    __shared__ float red[8];
    __shared__ float rsa[32];
    int bid = blockIdx.x, t = threadIdx.x;
    unsigned ph = 0;

    float* altx  = P.ws;                  // 65536
    float* bias0 = P.ws + 65536;          // 65536
    float* sres  = P.ws + 131072;         // 65536
    float* y     = P.ws + 196608;         // 65536
    float* s2    = P.ws + 262144;         // 65536
    float* sb2   = P.ws + 327680;         // 65536
    float* imv   = P.ws + 393216;         // 65536
    float* qkvs  = P.ws + 458752;         // 196608
    float* h     = P.ws + 655360;         // 262144
    float* pool  = P.ws + 917504;         // 2097152

    // ---------- phase 0: avgpool (all blocks) + sinusoidal bias (bid<32) ----------
    {
        int wv = t >> 6, lane = t & 63;
        int p = bid * 2 + (wv & 1);       // 0..2047
        int shalf = (wv >> 1) * 16;
        const float* row = P.x + (size_t)p * 2048;
        int c2 = p >> 6, c1 = p & 63;
        int m = c1 * 32 + c2;
        for (int sg = shalf; sg < shalf + 16; ++sg) {
            float v = row[sg * 64 + lane];
            for (int off = 32; off; off >>= 1) v += __shfl_xor(v, off, 64);
            if (lane == 0) altx[sg * 2048 + m] = v * (1.0f / 64.0f);
        }
        if (bid < 32) {
            const float kln = logf(10000.0f) / 1024.0f;
            for (int l = t; l < 2048; l += 256) {
                int c = l & ~1;
                float ang = (float)bid * expf(-(float)c * kln);
                bias0[bid * 2048 + l] = (l & 1) ? cosf(ang) : sinf(ang);
            }
        }
    }
    gsync(P.bar, ++ph * NBLK);
    // s partials = weight @ altx (8 splits)
    gemm256(P.weight, altx, pool, 2048, 2048, lAs, bid, t);
    gsync(P.bar, ++ph * NBLK);
    // sres = bias0 + sum(partials)
    if (bid < 256) {
        int idx = bid * 256 + t;
        float acc = bias0[idx];
        #pragma unroll
        for (int s = 0; s < 8; ++s) acc += pool[(size_t)s * 65536 + idx];
        sres[idx] = acc;
    }

    for (int a = 0; a < 3; ++a) {
        gsync(P.bar, ++ph * NBLK);
        // y = LN1(sres)
        if (bid < 32) ln_task(sres + bid * 2048, P.ln1_g, P.ln1_b, y + bid * 2048, 0, red, t);
        gsync(P.bar, ++ph * NBLK);
        gemm256(P.Wqkv + (size_t)a * 12582912, y, pool, 6144, 2048, lAs, bid, t);
        gsync(P.bar, ++ph * NBLK);
        // qkvs = sum of 8 qkv partials
        if (bid < 768) {
            int idx = bid * 256 + t;
            float acc = 0.f;
            #pragma unroll
            for (int s = 0; s < 8; ++s) acc += pool[(size_t)s * 196608 + idx];
            qkvs[idx] = acc;
        }
        gsync(P.bar, ++ph * NBLK);
        // scan: per-head scalar attn + serial cumsum
        if (bid < 16) {
            int hh = bid;
            int i = t >> 3, sub = t & 7;
            const float* qr = qkvs + (size_t)i * 6144 + hh * 128 + sub * 16;
            const float* kr = qr + 2048;
            float acc = 0.f;
            #pragma unroll
            for (int dd = 0; dd < 16; ++dd) acc += qr[dd] * kr[dd];
            acc += __shfl_xor(acc, 1, 64);
            acc += __shfl_xor(acc, 2, 64);
            acc += __shfl_xor(acc, 4, 64);
            if (sub == 0) rsa[i] = acc * 0.08838834764831845f;   // 1/sqrt(128)
            __syncthreads();
            if (t < 128) {
                float vs[32];
                #pragma unroll
                for (int i2 = 0; i2 < 32; ++i2)
                    vs[i2] = qkvs[(size_t)i2 * 6144 + 4096 + hh * 128 + t];
                float a2 = 0.f;
                #pragma unroll
                for (int i2 = 0; i2 < 32; ++i2) {
                    a2 += rsa[i2] * vs[i2];
                    imv[i2 * 2048 + hh * 128 + t] = a2;
                }
            }
        }
        gsync(P.bar, ++ph * NBLK);
        gemm256(P.Wo + (size_t)a * 4194304, imv, pool, 2048, 2048, lAs, bid, t);
        gsync(P.bar, ++ph * NBLK);
        // s2 = sres + sum(Wo partials)
        if (bid < 256) {
            int idx = bid * 256 + t;
            float acc = sres[idx];
            #pragma unroll
            for (int s = 0; s < 8; ++s) acc += pool[(size_t)s * 65536 + idx];
            s2[idx] = acc;
        }
        gsync(P.bar, ++ph * NBLK);
        // sb2 = LN2(s2) + s2
        if (bid < 32) ln_task(s2 + bid * 2048, P.ln2_g, P.ln2_b, sb2 + bid * 2048, 1, red, t);
        gsync(P.bar, ++ph * NBLK);
        gemm256(P.fc1_w, sb2, pool, 8192, 2048, lAs, bid, t);
        gsync(P.bar, ++ph * NBLK);
        // h = gelu(fc1_b + sum(fc1 partials))
        {
            int idx = bid * 256 + t;      // 262144 = 1024*256 exactly
            float v = P.fc1_b[idx & 8191];
            #pragma unroll
            for (int s = 0; s < 8; ++s) v += pool[(size_t)s * 262144 + idx];
            h[idx] = 0.5f * v * (1.0f + erff(v * 0.70710678118654752f));
        }
        gsync(P.bar, ++ph * NBLK);
        gemm256(P.fc2_w, h, pool, 2048, 8192, lAs, bid, t);
        gsync(P.bar, ++ph * NBLK);
        // s = fc2_b + sum(32 fc2 partials) -> sres (or out on last iter)
        if (bid < 256) {
            int idx = bid * 256 + t;
            float acc = P.fc2_b[idx & 2047];
            #pragma unroll
            for (int s = 0; s < 32; ++s) acc += pool[(size_t)s * 65536 + idx];
            float* dst = (a == 2) ? P.out : sres;
            dst[idx] = acc;
        }
    }
}

extern "C" void kernel_launch(void* const* d_in, const int* in_sizes, int n_in,
                              void* d_out, int out_size, void* d_ws, size_t ws_size,
                              hipStream_t stream) {
    Params P;
    P.x      = (const float*)d_in[0];
    P.weight = (const float*)d_in[1];
    P.Wqkv   = (const float*)d_in[2];
    P.Wo     = (const float*)d_in[3];
    P.ln1_g  = (const float*)d_in[4];
    P.ln1_b  = (const float*)d_in[5];
    P.ln2_g  = (const float*)d_in[6];
    P.ln2_b  = (const float*)d_in[7];
    P.fc1_w  = (const float*)d_in[8];
    P.fc1_b  = (const float*)d_in[9];
    P.fc2_w  = (const float*)d_in[10];
    P.fc2_b  = (const float*)d_in[11];
    P.ws     = (float*)d_ws;
    P.out    = (float*)d_out;
    P.bar    = (unsigned*)((float*)d_ws + (8u << 20));   // 32 MB in, far from data
    hipMemsetAsync(P.bar, 0, 64, stream);                // graph-capturable reset
    k_mega<<<NBLK, 256, 0, stream>>>(P);
}